// Round 7
// baseline (128.431 us; speedup 1.0000x reference)
//
#include <hip/hip_runtime.h>
#include <hip/hip_cooperative_groups.h>

namespace cg = cooperative_groups;

// FAVOR+ causal linear attention, fp32 I/O, bf16 MFMA chunked-GEMM form.
// B=2, L=4096, H=8, D=64, M=128, chunks C=64 x T=64.
// R7: single cooperative kernel kf = k1+k2+k3 fused with grid.sync().
// Rationale: k1/k3 have IDENTICAL per-thread mappings; Qf (33.6MB rw),
// n2 (33.6MB rw) and rsg existed only to carry per-thread register state
// across kernel boundaries. Fusing keeps qfr/nacc/rsv in VGPRs (-67MB
// traffic, -2 launch gaps). Grid 1024 = exactly 4 blocks/CU @ 40KB LDS
// (the R6 occupancy fix is what makes cooperative co-residency possible).
// Host falls back to the proven R6 3-kernel path if co-residency check
// fails (also catches VGPR overruns via the occupancy query).

#define B_ 2
#define L_ 4096
#define H_ 8
#define D_ 64
#define M_ 128
#define BH_ 16
#define HD_ 512
#define LHD_ (L_*HD_)
#define C_ 64
#define T_ 64
#define RATIO 0.08838834764831845f
#define EPS 1e-3f

#define REC_CS 8320                    // shorts per cs record: 64*128 KVt + 128 ks
#define REC_F  8192                    // shorts per Qf record (fallback path)
#define QF_OFF 8519680                 // shorts: 16*64*8320
#define N2_OFF 16908288                // shorts: QF_OFF + 16*64*8192 (f32 region)
#define RS_OFF 25296896                // shorts: N2_OFF + 2*4194304   (f32 region)
#define P_OFF  25427968                // shorts: RS_OFF + 131072; P bf16 [m][d]

// XOR-swizzles (bank-conflict-free, keep 8-short groups contiguous):
#define SWZ64(r,c)  ((r)*64  + ((c) ^ (((r)&7)*8)))
#define SWZ128(r,c) ((r)*128 + ((c) ^ (((r)&15)*8)))

typedef __attribute__((ext_vector_type(8))) short bf16x8;
typedef __attribute__((ext_vector_type(4))) short bf16x4;
typedef __attribute__((ext_vector_type(4))) float f32x4;

__device__ __forceinline__ short f2bf(float f) {
  union { float f; unsigned u; } x; x.f = f;
  unsigned r = (x.u + 0x7fffu + ((x.u >> 16) & 1u)) >> 16;
  return (short)r;
}
__device__ __forceinline__ float bf2f(short s) {
  union { unsigned u; float f; } x; x.u = ((unsigned)(unsigned short)s) << 16;
  return x.f;
}
__device__ __forceinline__ bf16x8 cvt8(float4 a, float4 b) {
  union { bf16x8 v; short s[8]; } u;
  u.s[0]=f2bf(a.x); u.s[1]=f2bf(a.y); u.s[2]=f2bf(a.z); u.s[3]=f2bf(a.w);
  u.s[4]=f2bf(b.x); u.s[5]=f2bf(b.y); u.s[6]=f2bf(b.z); u.s[7]=f2bf(b.w);
  return u.v;
}
#define MFMA(a,b,c) __builtin_amdgcn_mfma_f32_16x16x32_bf16((a),(b),(c),0,0,0)

// ---------------- k0: P -> bf16 once ----------------------------------------
__global__ __launch_bounds__(256) void k0(
    const float* __restrict__ P, unsigned short* __restrict__ ws)
{
  const int i = (blockIdx.x*256 + threadIdx.x)*4;   // 8 blocks * 256 * 4 = 8192
  float4 p4 = *(const float4*)(P + i);
  union { bf16x4 v; short s[4]; } u;
  u.s[0]=f2bf(p4.x); u.s[1]=f2bf(p4.y); u.s[2]=f2bf(p4.z); u.s[3]=f2bf(p4.w);
  *(bf16x4*)(ws + P_OFF + i) = u.v;
}

// ---------------- kf: fused cooperative kernel ------------------------------
__global__ __launch_bounds__(256, 4) void kf(
    const float* __restrict__ qq, const float* __restrict__ kk,
    const float* __restrict__ vv, unsigned short* __restrict__ ws,
    float* __restrict__ out)
{
  __shared__ short Vt[64*64];        // [d][t], SWZ64 (8KB); phase C: ks f32
  __shared__ short Kft[128*64];      // [m][t], SWZ64 (16KB); rows 0-63 -> Sm
  __shared__ short KfTM[64*128];     // [t][m], SWZ128 (16KB); phase C: csL

  const int tid = threadIdx.x, bid = blockIdx.x;
  const int bh = bid >> 6, c = bid & 63;
  const int b = bh >> 3, h = bh & 7;
  const int lane = tid & 63, w = tid >> 6, quad = lane >> 4, l15 = lane & 15;
  const size_t gbase = (size_t)b*LHD_ + (size_t)h*D_;
  const int t0 = c*T_;
  const int trow = 16*w + l15;
  const unsigned short* Pb = ws + P_OFF;

  // ===== Phase A (= R6 k1, minus Qf/rsg/n2 global stores) =====
  const float* qrow = qq + gbase + (size_t)(t0 + trow)*HD_;
  const float* krow = kk + gbase + (size_t)(t0 + trow)*HD_;
  float4 q4a = *(const float4*)(qrow + quad*8);
  float4 q4b = *(const float4*)(qrow + quad*8 + 4);
  float4 q4c = *(const float4*)(qrow + 32 + quad*8);
  float4 q4d = *(const float4*)(qrow + 32 + quad*8 + 4);
  float4 k4a = *(const float4*)(krow + quad*8);
  float4 k4b = *(const float4*)(krow + quad*8 + 4);
  float4 k4c = *(const float4*)(krow + 32 + quad*8);
  float4 k4d = *(const float4*)(krow + 32 + quad*8 + 4);

  for (int fi = tid; fi < 64*16; fi += 256) {
    int t = fi >> 4, d4 = (fi & 15)*4;
    float4 v4 = *(const float4*)(vv + gbase + (size_t)(t0+t)*HD_ + d4);
    Vt[SWZ64(d4+0, t)] = f2bf(v4.x);
    Vt[SWZ64(d4+1, t)] = f2bf(v4.y);
    Vt[SWZ64(d4+2, t)] = f2bf(v4.z);
    Vt[SWZ64(d4+3, t)] = f2bf(v4.w);
  }

  bf16x8 bq0 = cvt8(q4a, q4b), bq1 = cvt8(q4c, q4d);
  bf16x8 bk0 = cvt8(k4a, k4b), bk1 = cvt8(k4c, k4d);

  unsigned short* csb = ws + (size_t)(bh*C_+c)*REC_CS;

  bf16x4 qreg[8];
  #pragma unroll
  for (int ct = 0; ct < 8; ++ct) {
    bf16x8 ap0 = *(const bf16x8*)(Pb + (ct*16 + l15)*64 + quad*8);
    bf16x8 ap1 = *(const bf16x8*)(Pb + (ct*16 + l15)*64 + 32 + quad*8);
    f32x4 qa = {0.f,0.f,0.f,0.f}, ka = {0.f,0.f,0.f,0.f};
    qa = MFMA(ap0,bq0,qa); qa = MFMA(ap1,bq1,qa);
    ka = MFMA(ap0,bk0,ka); ka = MFMA(ap1,bk1,ka);
    union { bf16x4 v; short s[4]; } pq, pk;
    #pragma unroll
    for (int reg = 0; reg < 4; ++reg) {
      int m = 16*ct + 4*quad + reg;
      short qv = f2bf(fmaxf(qa[reg]*RATIO, 0.f) + EPS);
      short kv = f2bf(fmaxf(ka[reg]*RATIO, 0.f) + EPS);
      pq.s[reg] = qv; pk.s[reg] = kv;
      Kft[SWZ64(m, trow)] = kv;
    }
    qreg[ct] = pq.v;
    *(bf16x4*)&KfTM[SWZ128(trow, 16*ct + 4*quad)] = pk.v;
  }

  // Qf A-frags via in-wave 64-bit shuffles
  bf16x8 qfr[4];
  {
    const int src_lo = (2*(quad & 1))*16 + l15;
    #pragma unroll
    for (int ks2 = 0; ks2 < 4; ++ks2) {
      union { bf16x4 v; long long l; } a0, a1;
      a0.v = qreg[2*ks2]; a1.v = qreg[2*ks2+1];
      long long loA = __shfl(a0.l, src_lo, 64);
      long long hiA = __shfl(a0.l, src_lo + 16, 64);
      long long loB = __shfl(a1.l, src_lo, 64);
      long long hiB = __shfl(a1.l, src_lo + 16, 64);
      union { bf16x8 v8; long long l[2]; } r;
      r.l[0] = (quad < 2) ? loA : loB;
      r.l[1] = (quad < 2) ? hiA : hiB;
      qfr[ks2] = r.v8;
    }
  }
  __syncthreads();  // sync1: Vt, Kft, KfTM complete

  if (tid < 128) {
    float s = 0.f;
    #pragma unroll
    for (int i = 0; i < 8; ++i) {
      bf16x8 r = *(const bf16x8*)&Kft[SWZ64(tid, 8*i)];
      #pragma unroll
      for (int j = 0; j < 8; ++j) s += bf2f(r[j]);
    }
    csb[64*128 + tid] = (unsigned short)f2bf(s);
  }

  {
    bf16x8 av0 = *(const bf16x8*)&Vt[SWZ64(trow, 8*quad)];
    bf16x8 av1 = *(const bf16x8*)&Vt[SWZ64(trow, 32 + 8*quad)];
    #pragma unroll
    for (int mt = 0; mt < 8; ++mt) {
      bf16x8 b0 = *(const bf16x8*)&Kft[SWZ64(16*mt + l15, 8*quad)];
      bf16x8 b1 = *(const bf16x8*)&Kft[SWZ64(16*mt + l15, 32 + 8*quad)];
      f32x4 acc = {0.f,0.f,0.f,0.f};
      acc = MFMA(b0, av0, acc);
      acc = MFMA(b1, av1, acc);
      union { bf16x4 v; short s[4]; } pc;
      #pragma unroll
      for (int reg = 0; reg < 4; ++reg) pc.s[reg] = f2bf(acc[reg]);
      *(bf16x4*)(csb + trow*128 + 16*mt + 4*quad) = pc.v;
    }
  }

  // S = mask(Qf Kf^T)
  f32x4 sacc[4];
  #pragma unroll
  for (int jt = 0; jt < 4; ++jt) { f32x4 z = {0.f,0.f,0.f,0.f}; sacc[jt] = z; }
  #pragma unroll
  for (int ks2 = 0; ks2 < 4; ++ks2) {
    #pragma unroll
    for (int jt = 0; jt < 4; ++jt) {
      bf16x8 bb = *(const bf16x8*)&KfTM[SWZ128(16*jt + l15, 32*ks2 + 8*quad)];
      sacc[jt] = MFMA(qfr[ks2], bb, sacc[jt]);
    }
  }
  __syncthreads();  // sync2: Kft/KfTM reads done -> Kft rows 0-63 reusable

  short* Sm = Kft;
  float rs[4] = {0.f,0.f,0.f,0.f};
  #pragma unroll
  for (int jt = 0; jt < 4; ++jt)
    #pragma unroll
    for (int reg = 0; reg < 4; ++reg) {
      int row = 16*w + 4*quad + reg;
      int j = l15 + 16*jt;
      float val = (j <= row) ? sacc[jt][reg] : 0.f;
      rs[reg] += val;
      Sm[SWZ64(row, j)] = f2bf(val);
    }
  #pragma unroll
  for (int reg = 0; reg < 4; ++reg) {
    rs[reg] += __shfl_xor(rs[reg], 1);
    rs[reg] += __shfl_xor(rs[reg], 2);
    rs[reg] += __shfl_xor(rs[reg], 4);
    rs[reg] += __shfl_xor(rs[reg], 8);
  }
  // rsv for THIS thread's row trow=16w+l15 (stays in a register):
  float rsv_ = (l15 < 4) ? ((l15==0)?rs[0]:(l15==1)?rs[1]:(l15==2)?rs[2]:rs[3]) : 0.f;
  float rsv = __shfl(rsv_, ((l15 >> 2) << 4) + (l15 & 3), 64);

  // num2 = S V (stays in nacc registers)
  f32x4 nacc[4];
  #pragma unroll
  for (int ct = 0; ct < 4; ++ct) { f32x4 z = {0.f,0.f,0.f,0.f}; nacc[ct] = z; }
  #pragma unroll
  for (int kss = 0; kss < 2; ++kss) {
    bf16x8 sb = *(const bf16x8*)&Sm[SWZ64(trow, 32*kss + 8*quad)];
    #pragma unroll
    for (int ct = 0; ct < 4; ++ct) {
      bf16x8 a = *(const bf16x8*)&Vt[SWZ64(16*ct + l15, 32*kss + 8*quad)];
      nacc[ct] = MFMA(a, sb, nacc[ct]);
    }
  }

  // ===== Phase B: exclusive bf16 prefix over chunks (grid-wide) =====
  cg::this_grid().sync();

  if (bid < 130) {                       // 130*256 = 33280 = 16*2080 units
    const int gid = bid*256 + tid;
    const int pbh = gid / 2080, e = (gid % 2080)*4;
    unsigned short* base = ws + (size_t)pbh*C_*REC_CS + e;
    float run[4] = {0.f,0.f,0.f,0.f};
    #pragma unroll 1
    for (int batch = 0; batch < 8; ++batch) {
      bf16x4 pv[8];
      #pragma unroll
      for (int u = 0; u < 8; ++u)
        pv[u] = *(const bf16x4*)(base + (size_t)(batch*8+u)*REC_CS);
      #pragma unroll
      for (int u = 0; u < 8; ++u) {
        union { bf16x4 v; short s[4]; } wv;
        #pragma unroll
        for (int j = 0; j < 4; ++j) { wv.s[j] = f2bf(run[j]); run[j] += bf2f(pv[u][j]); }
        *(bf16x4*)(base + (size_t)(batch*8+u)*REC_CS) = wv.v;
      }
    }
  }

  cg::this_grid().sync();

  // ===== Phase C (= R6 k3, with qfr/nacc/rsv from registers) =====
  short* csL = KfTM;                 // dead after S
  float* ksL = (float*)Vt;           // dead after num2

  for (int i = tid; i < 1024; i += 256) {
    int row = i >> 4, cb = (i & 15)*8;
    *(bf16x8*)&csL[SWZ128(row, cb)] = *(const bf16x8*)(csb + i*8);
  }
  if (tid < 128) ksL[tid] = bf2f((short)csb[64*128 + tid]);
  __syncthreads();

  float dp = 0.f;
  #pragma unroll
  for (int ks2 = 0; ks2 < 4; ++ks2)
    #pragma unroll
    for (int j = 0; j < 8; ++j) dp += bf2f(qfr[ks2][j]) * ksL[ks2*32 + quad*8 + j];
  dp += __shfl_xor(dp, 16);
  dp += __shfl_xor(dp, 32);
  float inv = 1.f / (dp + rsv);

  f32x4 n1[4];
  #pragma unroll
  for (int ct = 0; ct < 4; ++ct) { f32x4 z = {0.f,0.f,0.f,0.f}; n1[ct] = z; }
  #pragma unroll
  for (int ks2 = 0; ks2 < 4; ++ks2) {
    #pragma unroll
    for (int ct = 0; ct < 4; ++ct) {
      bf16x8 a = *(const bf16x8*)&csL[SWZ128(16*ct + l15, 32*ks2 + 8*quad)];
      n1[ct] = MFMA(a, qfr[ks2], n1[ct]);
    }
  }
  const int tg = t0 + trow;
  #pragma unroll
  for (int ct = 0; ct < 4; ++ct) {
    float4 o;
    o.x = (n1[ct][0] + nacc[ct][0]) * inv;
    o.y = (n1[ct][1] + nacc[ct][1]) * inv;
    o.z = (n1[ct][2] + nacc[ct][2]) * inv;
    o.w = (n1[ct][3] + nacc[ct][3]) * inv;
    *(float4*)(out + gbase + (size_t)tg*HD_ + 16*ct + 4*quad) = o;
  }
}

// ================= Fallback path: proven R6 kernels ==========================
__global__ __launch_bounds__(256) void k1(
    const float* __restrict__ qq, const float* __restrict__ kk,
    const float* __restrict__ vv, unsigned short* __restrict__ ws)
{
  __shared__ short Vt[64*64];
  __shared__ short Kft[128*64];
  __shared__ short KfTM[64*128];

  const int tid = threadIdx.x, bid = blockIdx.x;
  const int bh = bid >> 6, c = bid & 63;
  const int b = bh >> 3, h = bh & 7;
  const int lane = tid & 63, w = tid >> 6, quad = lane >> 4, l15 = lane & 15;
  const size_t gbase = (size_t)b*LHD_ + (size_t)h*D_;
  const int t0 = c*T_;
  const int trow = 16*w + l15;
  const unsigned short* Pb = ws + P_OFF;

  const float* qrow = qq + gbase + (size_t)(t0 + trow)*HD_;
  const float* krow = kk + gbase + (size_t)(t0 + trow)*HD_;
  float4 q4a = *(const float4*)(qrow + quad*8);
  float4 q4b = *(const float4*)(qrow + quad*8 + 4);
  float4 q4c = *(const float4*)(qrow + 32 + quad*8);
  float4 q4d = *(const float4*)(qrow + 32 + quad*8 + 4);
  float4 k4a = *(const float4*)(krow + quad*8);
  float4 k4b = *(const float4*)(krow + quad*8 + 4);
  float4 k4c = *(const float4*)(krow + 32 + quad*8);
  float4 k4d = *(const float4*)(krow + 32 + quad*8 + 4);

  for (int fi = tid; fi < 64*16; fi += 256) {
    int t = fi >> 4, d4 = (fi & 15)*4;
    float4 v4 = *(const float4*)(vv + gbase + (size_t)(t0+t)*HD_ + d4);
    Vt[SWZ64(d4+0, t)] = f2bf(v4.x);
    Vt[SWZ64(d4+1, t)] = f2bf(v4.y);
    Vt[SWZ64(d4+2, t)] = f2bf(v4.z);
    Vt[SWZ64(d4+3, t)] = f2bf(v4.w);
  }

  bf16x8 bq0 = cvt8(q4a, q4b), bq1 = cvt8(q4c, q4d);
  bf16x8 bk0 = cvt8(k4a, k4b), bk1 = cvt8(k4c, k4d);

  unsigned short* qfb = ws + QF_OFF + (size_t)(bh*C_+c)*REC_F;
  unsigned short* csb = ws + (size_t)(bh*C_+c)*REC_CS;

  bf16x4 qreg[8];
  #pragma unroll
  for (int ct = 0; ct < 8; ++ct) {
    bf16x8 ap0 = *(const bf16x8*)(Pb + (ct*16 + l15)*64 + quad*8);
    bf16x8 ap1 = *(const bf16x8*)(Pb + (ct*16 + l15)*64 + 32 + quad*8);
    f32x4 qa = {0.f,0.f,0.f,0.f}, ka = {0.f,0.f,0.f,0.f};
    qa = MFMA(ap0,bq0,qa); qa = MFMA(ap1,bq1,qa);
    ka = MFMA(ap0,bk0,ka); ka = MFMA(ap1,bk1,ka);
    union { bf16x4 v; short s[4]; } pq, pk;
    #pragma unroll
    for (int reg = 0; reg < 4; ++reg) {
      int m = 16*ct + 4*quad + reg;
      short qv = f2bf(fmaxf(qa[reg]*RATIO, 0.f) + EPS);
      short kv = f2bf(fmaxf(ka[reg]*RATIO, 0.f) + EPS);
      pq.s[reg] = qv; pk.s[reg] = kv;
      Kft[SWZ64(m, trow)] = kv;
    }
    qreg[ct] = pq.v;
    *(bf16x4*)(qfb + trow*128 + 16*ct + 4*quad) = pq.v;
    *(bf16x4*)&KfTM[SWZ128(trow, 16*ct + 4*quad)] = pk.v;
  }

  bf16x8 qfr[4];
  {
    const int src_lo = (2*(quad & 1))*16 + l15;
    #pragma unroll
    for (int ks2 = 0; ks2 < 4; ++ks2) {
      union { bf16x4 v; long long l; } a0, a1;
      a0.v = qreg[2*ks2]; a1.v = qreg[2*ks2+1];
      long long loA = __shfl(a0.l, src_lo, 64);
      long long hiA = __shfl(a0.l, src_lo + 16, 64);
      long long loB = __shfl(a1.l, src_lo, 64);
      long long hiB = __shfl(a1.l, src_lo + 16, 64);
      union { bf16x8 v8; long long l[2]; } r;
      r.l[0] = (quad < 2) ? loA : loB;
      r.l[1] = (quad < 2) ? hiA : hiB;
      qfr[ks2] = r.v8;
    }
  }
  __syncthreads();

  if (tid < 128) {
    float s = 0.f;
    #pragma unroll
    for (int i = 0; i < 8; ++i) {
      bf16x8 r = *(const bf16x8*)&Kft[SWZ64(tid, 8*i)];
      #pragma unroll
      for (int j = 0; j < 8; ++j) s += bf2f(r[j]);
    }
    csb[64*128 + tid] = (unsigned short)f2bf(s);
  }

  {
    bf16x8 av0 = *(const bf16x8*)&Vt[SWZ64(trow, 8*quad)];
    bf16x8 av1 = *(const bf16x8*)&Vt[SWZ64(trow, 32 + 8*quad)];
    #pragma unroll
    for (int mt = 0; mt < 8; ++mt) {
      bf16x8 b0 = *(const bf16x8*)&Kft[SWZ64(16*mt + l15, 8*quad)];
      bf16x8 b1 = *(const bf16x8*)&Kft[SWZ64(16*mt + l15, 32 + 8*quad)];
      f32x4 acc = {0.f,0.f,0.f,0.f};
      acc = MFMA(b0, av0, acc);
      acc = MFMA(b1, av1, acc);
      union { bf16x4 v; short s[4]; } pc;
      #pragma unroll
      for (int reg = 0; reg < 4; ++reg) pc.s[reg] = f2bf(acc[reg]);
      *(bf16x4*)(csb + trow*128 + 16*mt + 4*quad) = pc.v;
    }
  }

  f32x4 sacc[4];
  #pragma unroll
  for (int jt = 0; jt < 4; ++jt) { f32x4 z = {0.f,0.f,0.f,0.f}; sacc[jt] = z; }
  #pragma unroll
  for (int ks2 = 0; ks2 < 4; ++ks2) {
    #pragma unroll
    for (int jt = 0; jt < 4; ++jt) {
      bf16x8 bb = *(const bf16x8*)&KfTM[SWZ128(16*jt + l15, 32*ks2 + 8*quad)];
      sacc[jt] = MFMA(qfr[ks2], bb, sacc[jt]);
    }
  }
  __syncthreads();

  short* Sm = Kft;
  float rs[4] = {0.f,0.f,0.f,0.f};
  #pragma unroll
  for (int jt = 0; jt < 4; ++jt)
    #pragma unroll
    for (int reg = 0; reg < 4; ++reg) {
      int row = 16*w + 4*quad + reg;
      int j = l15 + 16*jt;
      float val = (j <= row) ? sacc[jt][reg] : 0.f;
      rs[reg] += val;
      Sm[SWZ64(row, j)] = f2bf(val);
    }
  #pragma unroll
  for (int reg = 0; reg < 4; ++reg) {
    rs[reg] += __shfl_xor(rs[reg], 1);
    rs[reg] += __shfl_xor(rs[reg], 2);
    rs[reg] += __shfl_xor(rs[reg], 4);
    rs[reg] += __shfl_xor(rs[reg], 8);
  }
  float* rsg = (float*)(ws + RS_OFF);
  if (l15 < 4) {
    float v = (l15==0) ? rs[0] : (l15==1) ? rs[1] : (l15==2) ? rs[2] : rs[3];
    rsg[bh*L_ + t0 + 16*w + 4*quad + l15] = v;
  }

  float* n2 = (float*)(ws + N2_OFF);
  f32x4 nacc[4];
  #pragma unroll
  for (int ct = 0; ct < 4; ++ct) { f32x4 z = {0.f,0.f,0.f,0.f}; nacc[ct] = z; }
  #pragma unroll
  for (int kss = 0; kss < 2; ++kss) {
    bf16x8 sb = *(const bf16x8*)&Sm[SWZ64(trow, 32*kss + 8*quad)];
    #pragma unroll
    for (int ct = 0; ct < 4; ++ct) {
      bf16x8 a = *(const bf16x8*)&Vt[SWZ64(16*ct + l15, 32*kss + 8*quad)];
      nacc[ct] = MFMA(a, sb, nacc[ct]);
    }
  }
  const int tg = t0 + trow;
  #pragma unroll
  for (int ct = 0; ct < 4; ++ct) {
    float4 o;
    o.x = nacc[ct][0]; o.y = nacc[ct][1]; o.z = nacc[ct][2]; o.w = nacc[ct][3];
    *(float4*)(n2 + gbase + (size_t)tg*HD_ + 16*ct + 4*quad) = o;
  }
}

__global__ __launch_bounds__(64) void k2(unsigned short* __restrict__ ws)
{
  const int gid = blockIdx.x*64 + threadIdx.x;
  const int bh = gid / 2080, e = (gid % 2080)*4;
  unsigned short* base = ws + (size_t)bh*C_*REC_CS + e;
  bf16x4 v[64];
  #pragma unroll
  for (int c2 = 0; c2 < 64; ++c2) v[c2] = *(const bf16x4*)(base + (size_t)c2*REC_CS);
  float run[4] = {0.f,0.f,0.f,0.f};
  #pragma unroll
  for (int c2 = 0; c2 < 64; ++c2) {
    union { bf16x4 v; short s[4]; } wv;
    #pragma unroll
    for (int j = 0; j < 4; ++j) { wv.s[j] = f2bf(run[j]); run[j] += bf2f(v[c2][j]); }
    *(bf16x4*)(base + (size_t)c2*REC_CS) = wv.v;
  }
}

__global__ __launch_bounds__(256) void k3(
    const unsigned short* __restrict__ ws, float* __restrict__ out)
{
  __shared__ short csL[64*128];
  __shared__ float ks_lds[128];

  const int tid = threadIdx.x, bid = blockIdx.x;
  const int bh = bid >> 6, c = bid & 63;
  const int b = bh >> 3, h = bh & 7;
  const int lane = tid & 63, w = tid >> 6, quad = lane >> 4, l15 = lane & 15;
  const size_t gbase = (size_t)b*LHD_ + (size_t)h*D_;
  const int t0 = c*T_;
  const unsigned short* csb = ws + (size_t)(bh*C_+c)*REC_CS;
  const unsigned short* qfb = ws + QF_OFF + (size_t)(bh*C_+c)*REC_F;
  const float* n2 = (const float*)(ws + N2_OFF);
  const float* rsg = (const float*)(ws + RS_OFF);
  const int trow = 16*w + l15;
  const int tg = t0 + trow;

  for (int i = tid; i < 1024; i += 256) {
    int row = i >> 4, cb = (i & 15)*8;
    *(bf16x8*)&csL[SWZ128(row, cb)] = *(const bf16x8*)(csb + i*8);
  }
  if (tid < 128) ks_lds[tid] = bf2f((short)csb[64*128 + tid]);

  float4 nv[4];
  #pragma unroll
  for (int ct = 0; ct < 4; ++ct)
    nv[ct] = *(const float4*)(n2 + gbase + (size_t)tg*HD_ + 16*ct + 4*quad);
  float rsv = rsg[bh*L_ + tg];
  bf16x8 qfB[4];
  #pragma unroll
  for (int ks2 = 0; ks2 < 4; ++ks2)
    qfB[ks2] = *(const bf16x8*)(qfb + trow*128 + ks2*32 + quad*8);

  __syncthreads();

  float dp = 0.f;
  #pragma unroll
  for (int ks2 = 0; ks2 < 4; ++ks2)
    #pragma unroll
    for (int j = 0; j < 8; ++j) dp += bf2f(qfB[ks2][j]) * ks_lds[ks2*32 + quad*8 + j];
  dp += __shfl_xor(dp, 16);
  dp += __shfl_xor(dp, 32);
  float inv = 1.f / (dp + rsv);

  f32x4 nacc[4];
  #pragma unroll
  for (int ct = 0; ct < 4; ++ct) { f32x4 z = {0.f,0.f,0.f,0.f}; nacc[ct] = z; }
  #pragma unroll
  for (int ks2 = 0; ks2 < 4; ++ks2) {
    #pragma unroll
    for (int ct = 0; ct < 4; ++ct) {
      bf16x8 a = *(const bf16x8*)&csL[SWZ128(16*ct + l15, 32*ks2 + 8*quad)];
      nacc[ct] = MFMA(a, qfB[ks2], nacc[ct]);
    }
  }
  #pragma unroll
  for (int ct = 0; ct < 4; ++ct) {
    float4 o;
    o.x = (nacc[ct][0] + nv[ct].x) * inv;
    o.y = (nacc[ct][1] + nv[ct].y) * inv;
    o.z = (nacc[ct][2] + nv[ct].z) * inv;
    o.w = (nacc[ct][3] + nv[ct].w) * inv;
    *(float4*)(out + gbase + (size_t)tg*HD_ + 16*ct + 4*quad) = o;
  }
}

extern "C" void kernel_launch(void* const* d_in, const int* in_sizes, int n_in,
                              void* d_out, int out_size, void* d_ws, size_t ws_size,
                              hipStream_t stream) {
  const float* q = (const float*)d_in[0];
  const float* k = (const float*)d_in[1];
  const float* v = (const float*)d_in[2];
  const float* P = (const float*)d_in[3];
  float* out = (float*)d_out;
  unsigned short* ws = (unsigned short*)d_ws;  // needs ~50.9 MB

  // One-time co-residency check for the cooperative fused kernel.
  static int coop_ok = -1;
  if (coop_ok < 0) {
    int nb = 0, cus = 0;
    hipError_t e1 = hipOccupancyMaxActiveBlocksPerMultiprocessor(&nb, kf, 256, 0);
    hipError_t e2 = hipDeviceGetAttribute(&cus, hipDeviceAttributeMultiprocessorCount, 0);
    coop_ok = (e1 == hipSuccess && e2 == hipSuccess && nb * cus >= BH_*C_) ? 1 : 0;
  }

  k0<<<dim3(8), dim3(256), 0, stream>>>(P, ws);

  if (coop_ok) {
    void* args[] = { (void*)&q, (void*)&k, (void*)&v, (void*)&ws, (void*)&out };
    hipError_t e = hipLaunchCooperativeKernel(kf, dim3(BH_*C_), dim3(256),
                                              args, 0, stream);
    if (e == hipSuccess) return;
    coop_ok = 0;  // fall through to the proven 3-kernel path
  }

  k1<<<dim3(BH_*C_), dim3(256), 0, stream>>>(q, k, v, ws);
  k2<<<dim3(520),    dim3(64),  0, stream>>>(ws);
  k3<<<dim3(BH_*C_), dim3(256), 0, stream>>>(ws, out);
}